// Round 9
// baseline (800.506 us; speedup 1.0000x reference)
//
#include <hip/hip_runtime.h>
#include <math.h>

#define D 64
#define ED 16
#define NEG 0.2f
#define BN_EPS 1e-5f

// ---------------- CSR construction ----------------

__global__ void k_count(const int* __restrict__ dst, int* __restrict__ cnt,
                        float* __restrict__ stat, int e) {
    int i = blockIdx.x * blockDim.x + threadIdx.x;
    if (blockIdx.x == 0 && threadIdx.x < 256) stat[threadIdx.x] = 0.f;  // zero BN stat bufs
    if (i < e) atomicAdd(&cnt[dst[i]], 1);
}

// hierarchical scan (R4-proven; single-block scanall cost ~80us)
__global__ void k_scan1(const int* __restrict__ cnt, int* __restrict__ off,
                        int* __restrict__ bsum, int n) {
    __shared__ int buf[1024];
    int i = blockIdx.x * 1024 + threadIdx.x;
    int v = (i < n) ? cnt[i] : 0;
    buf[threadIdx.x] = v;
    __syncthreads();
    for (int d = 1; d < 1024; d <<= 1) {
        int t = (threadIdx.x >= (unsigned)d) ? buf[threadIdx.x - d] : 0;
        __syncthreads();
        buf[threadIdx.x] += t;
        __syncthreads();
    }
    if (i < n) off[i + 1] = buf[threadIdx.x];
    if (threadIdx.x == 1023) bsum[blockIdx.x] = buf[1023];
    if (i == 0) off[0] = 0;
}

__global__ void k_scan2(int* __restrict__ bsum, int nb) {
    int l = threadIdx.x;
    int v = (l < nb) ? bsum[l] : 0;
    #pragma unroll
    for (int o = 1; o < 64; o <<= 1) {
        int t = __shfl_up(v, o, 64);
        if (l >= o) v += t;
    }
    int ex = __shfl_up(v, 1, 64);
    if (l == 0) ex = 0;
    if (l < nb) bsum[l] = ex;
}

__global__ void k_scan3(int* __restrict__ off, const int* __restrict__ bsum, int n) {
    int i = blockIdx.x * blockDim.x + threadIdx.x;
    if (i < n) off[i + 1] += bsum[i >> 10];
}

// place edges: only the 4B eid scatter is uncoalesced (reuses cnt as fill)
__global__ void k_scatter(const int* __restrict__ dst, const int* __restrict__ off,
                          int* __restrict__ cnt, int* __restrict__ eid, int e) {
    int i = blockIdx.x * blockDim.x + threadIdx.x;
    if (i < e) {
        int d = dst[i];
        int r = atomicSub(&cnt[d], 1);          // r in [1..deg]
        eid[off[d] + r - 1] = i;
    }
}

// permute srcs + edge_attr into CSR order: coalesced writes, scattered reads
__global__ void k_permute(const int* __restrict__ eid, const int* __restrict__ src,
                          const float4* __restrict__ ea4, int* __restrict__ srcs,
                          float4* __restrict__ eas4, int e) {
    int p = blockIdx.x * blockDim.x + threadIdx.x;
    if (p < e) {
        int i = eid[p];
        srcs[p] = src[i];
        size_t qi = 4 * (size_t)i, qp = 4 * (size_t)p;
        float4 a0 = ea4[qi], a1 = ea4[qi + 1], a2 = ea4[qi + 2], a3 = ea4[qi + 3];
        eas4[qp] = a0; eas4[qp + 1] = a1; eas4[qp + 2] = a2; eas4[qp + 3] = a3;
    }
}

// ---------------- gemm: xl/xr = BN'(h) @ {Wl,Wr}; BN finalize folded in ----------------

__global__ __launch_bounds__(256) void k_gemm(
        const float* __restrict__ h, const float* __restrict__ Wl,
        const float* __restrict__ Wr, float* __restrict__ xl,
        float* __restrict__ xr, const float* __restrict__ stat,
        const float* __restrict__ gamma, const float* __restrict__ beta,
        int mode, int n) {
    int lane = threadIdx.x & 63;
    float wl[D], wr[D];
    #pragma unroll
    for (int k = 0; k < D; ++k) { wl[k] = Wl[k * D + lane]; wr[k] = Wr[k * D + lane]; }
    float sc = 1.f, sh = 0.f;
    if (mode) {
        float s = stat[lane], q = stat[64 + lane];
        float mean = s / (float)n;
        float var  = q / (float)n - mean * mean;
        sc = gamma[lane] * rsqrtf(var + BN_EPS);
        sh = beta[lane] - mean * sc;
    }
    int wid = blockIdx.x * (blockDim.x >> 6) + (threadIdx.x >> 6);
    int nw  = gridDim.x * (blockDim.x >> 6);
    for (int r0 = wid * 2; r0 < n; r0 += nw * 2) {
        int r1 = r0 + 1;
        float h0 = h[(size_t)r0 * D + lane];
        float h1 = (r1 < n) ? h[(size_t)r1 * D + lane] : 0.f;
        if (mode) {
            h0 = h0 * sc + sh; h1 = h1 * sc + sh;
            if (mode == 2) {
                h0 = (h0 > 0.f) ? h0 : expm1f(h0);
                h1 = (h1 > 0.f) ? h1 : expm1f(h1);
            }
        }
        float a0 = 0.f, b0 = 0.f, a1 = 0.f, b1 = 0.f;
        #pragma unroll
        for (int k = 0; k < D; ++k) {
            float x0 = __shfl(h0, k, 64);
            float x1 = __shfl(h1, k, 64);
            a0 += x0 * wl[k]; b0 += x0 * wr[k];
            a1 += x1 * wl[k]; b1 += x1 * wr[k];
        }
        xl[(size_t)r0 * D + lane] = a0; xr[(size_t)r0 * D + lane] = b0;
        if (r1 < n) { xl[(size_t)r1 * D + lane] = a1; xr[(size_t)r1 * D + lane] = b1; }
    }
}

// ---------------- fused GATv2 ----------------
// wave = node; 16-lane group g = 2 edge slots (8 edges/pack) for doubled MLP.
// 1-deep prefetch of srcs+eas; xl gathers issued mid-iteration under the EEV FMAs.
// Raw exp softmax (logits O(1-10); exact after normalization). Self-loop
// ee = sum of masked per-edge eev / deg. BN stats via LDS atomics.
// __launch_bounds__(256,4) = loose 128-VGPR cap (m69 occupancy cliff); R6's (256,8)
// 64-cap spilled catastrophically — WRITE_SIZE is the spill guard.

#define EEVF(c, u0, u1, u2, u3) \
    (u0.x*we[0].c + u0.y*we[1].c + u0.z*we[2].c + u0.w*we[3].c \
   + u1.x*we[4].c + u1.y*we[5].c + u1.z*we[6].c + u1.w*we[7].c \
   + u2.x*we[8].c + u2.y*we[9].c + u2.z*we[10].c + u2.w*we[11].c \
   + u3.x*we[12].c + u3.y*we[13].c + u3.z*we[14].c + u3.w*we[15].c)

__global__ __launch_bounds__(256, 4) void k_gat(
        const float4* __restrict__ xl4, const float4* __restrict__ xr4,
        const float4* __restrict__ eas4, const int* __restrict__ srcs,
        const int* __restrict__ off,
        const float4* __restrict__ We4, const float4* __restrict__ att4,
        const float4* __restrict__ bias4, float* __restrict__ out,
        float* __restrict__ stat, int n, int do_elu) {
    __shared__ float ls[128];
    if (threadIdx.x < 128) ls[threadIdx.x] = 0.f;
    __syncthreads();
    int lane = threadIdx.x & 63;
    int g = lane >> 4, c16 = lane & 15;
    float4 we[ED];
    #pragma unroll
    for (int j = 0; j < ED; ++j) we[j] = We4[j * 16 + c16];
    float4 av = att4[c16];
    int wid = blockIdx.x * (blockDim.x >> 6) + (threadIdx.x >> 6);
    int nw  = gridDim.x * (blockDim.x >> 6);
    for (int i = wid; i < n; i += nw) {
        int beg = off[i], end = off[i + 1];
        float4 xrv = xr4[(size_t)i * 16 + c16];
        float denom = 0.f;
        float ax = 0.f, ay = 0.f, az = 0.f, aw = 0.f;
        float ex = 0.f, ey = 0.f, ez = 0.f, ew = 0.f;
        if (beg < end) {
            int rem0 = end - beg;
            int aA = (g < rem0), aB = (g + 4 < rem0);
            int pA = beg + (aA ? g : 0);
            int pB = beg + (aB ? g + 4 : 0);
            int sA = srcs[pA], sB = srcs[pB];
            size_t qA = 4 * (size_t)pA, qB = 4 * (size_t)pB;
            float4 a0 = eas4[qA], a1 = eas4[qA + 1], a2 = eas4[qA + 2], a3 = eas4[qA + 3];
            float4 b0 = eas4[qB], b1 = eas4[qB + 1], b2 = eas4[qB + 2], b3 = eas4[qB + 3];
            float4 XA = xl4[(size_t)sA * 16 + c16];
            float4 XB = xl4[(size_t)sB * 16 + c16];
            for (int pos = beg; pos < end; pos += 8) {
                int posn = pos + 8;
                int remn = end - posn;
                int anA = (remn > 0) && (g < remn);
                int anB = (remn > 0) && (g + 4 < remn);
                int pnA = (remn > 0) ? posn + (anA ? g : 0) : pos;
                int pnB = (remn > 0) ? posn + (anB ? g + 4 : 0) : pos;
                int snA = srcs[pnA], snB = srcs[pnB];        // next srcs
                size_t qnA = 4 * (size_t)pnA, qnB = 4 * (size_t)pnB;
                float4 na0 = eas4[qnA],     na1 = eas4[qnA + 1];
                float4 na2 = eas4[qnA + 2], na3 = eas4[qnA + 3];
                float4 nb0 = eas4[qnB],     nb1 = eas4[qnB + 1];
                float4 nb2 = eas4[qnB + 2], nb3 = eas4[qnB + 3];
                // EEVs for current pack (cover snA/snB latency)
                float eexA = EEVF(x, a0, a1, a2, a3), eeyA = EEVF(y, a0, a1, a2, a3);
                float eezA = EEVF(z, a0, a1, a2, a3), eewA = EEVF(w, a0, a1, a2, a3);
                float eexB = EEVF(x, b0, b1, b2, b3), eeyB = EEVF(y, b0, b1, b2, b3);
                float eezB = EEVF(z, b0, b1, b2, b3), eewB = EEVF(w, b0, b1, b2, b3);
                float4 xnA = xl4[(size_t)snA * 16 + c16];    // sn arrived during EEV
                float4 xnB = xl4[(size_t)snB * 16 + c16];
                float mkA = aA ? 1.f : 0.f, mkB = aB ? 1.f : 0.f;
                ex += mkA * eexA + mkB * eexB;
                ey += mkA * eeyA + mkB * eeyB;
                ez += mkA * eezA + mkB * eezB;
                ew += mkA * eewA + mkB * eewB;
                float mxA = XA.x + xrv.x + eexA, myA = XA.y + xrv.y + eeyA;
                float mzA = XA.z + xrv.z + eezA, mwA = XA.w + xrv.w + eewA;
                float mxB = XB.x + xrv.x + eexB, myB = XB.y + xrv.y + eeyB;
                float mzB = XB.z + xrv.z + eezB, mwB = XB.w + xrv.w + eewB;
                float pA0 = fmaxf(mxA, NEG * mxA) * av.x + fmaxf(myA, NEG * myA) * av.y
                          + fmaxf(mzA, NEG * mzA) * av.z + fmaxf(mwA, NEG * mwA) * av.w;
                float pB0 = fmaxf(mxB, NEG * mxB) * av.x + fmaxf(myB, NEG * myB) * av.y
                          + fmaxf(mzB, NEG * mzB) * av.z + fmaxf(mwB, NEG * mwB) * av.w;
                #pragma unroll
                for (int o = 1; o <= 8; o <<= 1) {           // 2 independent butterflies
                    pA0 += __shfl_xor(pA0, o, 64);
                    pB0 += __shfl_xor(pB0, o, 64);
                }
                float evA = aA ? __expf(pA0) : 0.f;
                float evB = aB ? __expf(pB0) : 0.f;
                denom += evA + evB;
                ax += evA * XA.x + evB * XB.x;
                ay += evA * XA.y + evB * XB.y;
                az += evA * XA.z + evB * XB.z;
                aw += evA * XA.w + evB * XB.w;
                a0 = na0; a1 = na1; a2 = na2; a3 = na3;
                b0 = nb0; b1 = nb1; b2 = nb2; b3 = nb3;
                XA = xnA; XB = xnB; aA = anA; aB = anB;
            }
        }
        // merge 4 per-group partials — plain sums
        #pragma unroll
        for (int o = 16; o <= 32; o <<= 1) {
            denom += __shfl_xor(denom, o, 64);
            ax += __shfl_xor(ax, o, 64);
            ay += __shfl_xor(ay, o, 64);
            az += __shfl_xor(az, o, 64);
            aw += __shfl_xor(aw, o, 64);
            ex += __shfl_xor(ex, o, 64);
            ey += __shfl_xor(ey, o, 64);
            ez += __shfl_xor(ez, o, 64);
            ew += __shfl_xor(ew, o, 64);
        }
        // self-loop (loop_attr@We == mean of incoming eev; 0 if deg==0)
        int deg = end - beg;
        float inv = (deg > 0) ? 1.f / (float)deg : 0.f;
        float4 xli = xl4[(size_t)i * 16 + c16];
        float mx = xli.x + xrv.x + ex * inv;
        float my = xli.y + xrv.y + ey * inv;
        float mz = xli.z + xrv.z + ez * inv;
        float mw = xli.w + xrv.w + ew * inv;
        float p0 = fmaxf(mx, NEG * mx) * av.x + fmaxf(my, NEG * my) * av.y
                 + fmaxf(mz, NEG * mz) * av.z + fmaxf(mw, NEG * mw) * av.w;
        #pragma unroll
        for (int o = 1; o <= 8; o <<= 1) p0 += __shfl_xor(p0, o, 64);
        float ev = __expf(p0);
        denom += ev;
        ax += ev * xli.x;
        ay += ev * xli.y;
        az += ev * xli.z;
        aw += ev * xli.w;
        float invd = 1.f / denom;
        float4 b4 = bias4[c16];
        float ox = ax * invd + b4.x;
        float oy = ay * invd + b4.y;
        float oz = az * invd + b4.z;
        float ow = aw * invd + b4.w;
        if (do_elu) {
            ox = (ox > 0.f) ? ox : expm1f(ox);
            oy = (oy > 0.f) ? oy : expm1f(oy);
            oz = (oz > 0.f) ? oz : expm1f(oz);
            ow = (ow > 0.f) ? ow : expm1f(ow);
        }
        if (g == 0) {
            float4 o4; o4.x = ox; o4.y = oy; o4.z = oz; o4.w = ow;
            ((float4*)out)[(size_t)i * 16 + c16] = o4;
            if (stat) {
                atomicAdd(&ls[c16 * 4 + 0], ox);
                atomicAdd(&ls[c16 * 4 + 1], oy);
                atomicAdd(&ls[c16 * 4 + 2], oz);
                atomicAdd(&ls[c16 * 4 + 3], ow);
                atomicAdd(&ls[64 + c16 * 4 + 0], ox * ox);
                atomicAdd(&ls[64 + c16 * 4 + 1], oy * oy);
                atomicAdd(&ls[64 + c16 * 4 + 2], oz * oz);
                atomicAdd(&ls[64 + c16 * 4 + 3], ow * ow);
            }
        }
    }
    if (stat) {
        __syncthreads();
        if (threadIdx.x < 128) atomicAdd(&stat[threadIdx.x], ls[threadIdx.x]);
    }
}

// ---------------- launch ----------------

extern "C" void kernel_launch(void* const* d_in, const int* in_sizes, int n_in,
                              void* d_out, int out_size, void* d_ws, size_t ws_size,
                              hipStream_t stream) {
    const float* x     = (const float*)d_in[0];
    const int*   ei    = (const int*)d_in[1];
    const float* ea    = (const float*)d_in[2];
    const float* Wl    = (const float*)d_in[3];
    const float* Wr    = (const float*)d_in[4];
    const float* We    = (const float*)d_in[5];
    const float* att   = (const float*)d_in[6];
    const float* bias  = (const float*)d_in[7];
    const float* gamma = (const float*)d_in[8];
    const float* beta  = (const float*)d_in[9];
    float* out = (float*)d_out;

    int n = in_sizes[0] / D;
    int e = in_sizes[1] / 2;
    const int* src = ei;
    const int* dst = ei + e;
    int nb = (n + 1023) / 1024;

    float* xl   = (float*)d_ws;
    float* xr   = xl + (size_t)n * D;
    float* hbuf = xr + (size_t)n * D;
    float* stat = hbuf + (size_t)n * D;        // [2][128]: raw {sum,sq} per BN
    float* eas  = stat + 256;                   // [e][16] pre-sorted edge_attr
    int* cnt  = (int*)(eas + (size_t)e * ED);
    int* off  = cnt + n;
    int* bsum = off + n + 1;
    int* srcs = bsum + 256;
    int* eid  = srcs + e;

    hipMemsetAsync(cnt, 0, (size_t)n * sizeof(int), stream);
    k_count<<<(e + 255) / 256, 256, 0, stream>>>(dst, cnt, stat, e);
    k_scan1<<<nb, 1024, 0, stream>>>(cnt, off, bsum, n);
    k_scan2<<<1, 64, 0, stream>>>(bsum, nb);
    k_scan3<<<(n + 255) / 256, 256, 0, stream>>>(off, bsum, n);
    k_scatter<<<(e + 255) / 256, 256, 0, stream>>>(dst, off, cnt, eid, e);
    k_permute<<<(e + 255) / 256, 256, 0, stream>>>(eid, src, (const float4*)ea,
                                                   srcs, (float4*)eas, e);

    const int gemm_grid = 1024;
    const int gat_grid  = 2048;

    // layer 0: conv -> ELU (in gat) -> BN0 stats (epilogue); BN0 apply folded into gemm1
    k_gemm<<<gemm_grid, 256, 0, stream>>>(x, Wl, Wr, xl, xr, stat, gamma, beta, 0, n);
    k_gat<<<gat_grid, 256, 0, stream>>>((const float4*)xl, (const float4*)xr,
                                        (const float4*)eas, srcs, off,
                                        (const float4*)We, (const float4*)att,
                                        (const float4*)bias, hbuf, stat, n, 1);
    // layer 1: conv (BN0 folded) -> BN1 stats (epilogue); BN1+ELU folded into gemm2
    k_gemm<<<gemm_grid, 256, 0, stream>>>(hbuf, Wl + D * D, Wr + D * D, xl, xr,
                                          stat, gamma, beta, 1, n);
    k_gat<<<gat_grid, 256, 0, stream>>>((const float4*)xl, (const float4*)xr,
                                        (const float4*)eas, srcs, off,
                                        (const float4*)(We + ED * D), (const float4*)(att + D),
                                        (const float4*)(bias + D), hbuf, stat + 128, n, 0);
    // layer 2: conv (BN1+ELU folded) -> out
    k_gemm<<<gemm_grid, 256, 0, stream>>>(hbuf, Wl + 2 * D * D, Wr + 2 * D * D, xl, xr,
                                          stat + 128, gamma + D, beta + D, 2, n);
    k_gat<<<gat_grid, 256, 0, stream>>>((const float4*)xl, (const float4*)xr,
                                        (const float4*)eas, srcs, off,
                                        (const float4*)(We + 2 * ED * D), (const float4*)(att + 2 * D),
                                        (const float4*)(bias + 2 * D), out, (float*)nullptr, n, 0);
}